// Round 1
// baseline (28.766 us; speedup 1.0000x reference)
//
#include <hip/hip_runtime.h>
#include <math.h>

// Problem constants (fixed by the reference's setup_inputs)
#define NE_TOTAL   32768   // B*T = 8*4096
#define EPB        32      // elements per block
#define THREADS    256
#define NI         9       // NUM_INITIAL
#define NT         17      // TOTAL_NODES
#define DTOT       8       // digit slots
#define NBASE      10
#define DEPTH      8

#define MAG_MAX    1e28f
#define MAG_MIN    1e-12f
#define LOG_LIM    100.0f

// fast saturating tanh: 1 - 2/(e^{2x}+1); exact ±1 in saturation, handles inf
__device__ __forceinline__ float tanh_fast(float x) {
    // clamp arg so __expf stays finite-ish; beyond |x|>44 result is exactly +-1 in f32
    float e = __expf(2.0f * x);          // e in [0, inf]
    return 1.0f - 2.0f / (e + 1.0f);     // inf -> 1, 0 -> -1
}

__global__ __launch_bounds__(THREADS, 4)
void dag_exec_kernel(const float* __restrict__ dl,   // [NE,9,8,10]
                     const float* __restrict__ vsg,  // [NE,17]
                     const float* __restrict__ Og,   // [NE,8,17]
                     const float* __restrict__ Gg,   // [NE,8]
                     float* __restrict__ out)        // [NE]
{
    // padded strides: 73,137,17,9 are all coprime-ish with 32 banks (mod 32 = 9,9,17,9)
    __shared__ float s_slot[EPB * 73];     // expected*power per (elem, node*8+d)
    __shared__ float s_O[EPB * 137];       // 136 -> 137 padded
    __shared__ float s_vs[EPB * NT];       // stride 17, conflict-free
    __shared__ float s_G[EPB * 9];         // 8 -> 9 padded

    const int tid = threadIdx.x;
    const long e0 = (long)blockIdx.x * EPB;

    // ---- stage O: 32*136 = 4352 = 17*256 floats, coalesced ----
    {
        const float* Ob = Og + e0 * (DEPTH * NT);
        #pragma unroll
        for (int k = 0; k < 17; ++k) {
            int g = tid + k * THREADS;           // 0..4351
            int el = g / 136;
            int rem = g - el * 136;
            s_O[el * 137 + rem] = Ob[g];
        }
    }
    // ---- stage V_sign: 544 floats ----
    {
        const float* Vb = vsg + e0 * NT;
        s_vs[tid] = Vb[tid];
        s_vs[tid + 256] = Vb[tid + 256];
        if (tid < 32) s_vs[tid + 512] = Vb[tid + 512];
    }
    // ---- stage G: 256 floats ----
    {
        int el = tid >> 3, rem = tid & 7;
        s_G[el * 9 + rem] = Gg[e0 * DEPTH + tid];
    }

    // ---- phase 1: softmax slots. 32 elems * 72 slots = 2304 = 9*256 ----
    {
        const int d = tid & 7;                   // since 256 % 8 == 0, d is constant over k
        float powv = (d == 0) ? 1000.0f : (d == 1) ? 100.0f : (d == 2) ? 10.0f :
                     (d == 3) ? 1.0f    : (d == 4) ? 0.1f   : (d == 5) ? 0.01f :
                     (d == 6) ? 0.001f  : 0.0001f;
        const float* Db = dl + e0 * (NI * DTOT * NBASE);
        #pragma unroll
        for (int k = 0; k < 9; ++k) {
            int s = tid + k * THREADS;           // 0..2303
            const float* p = Db + (long)s * NBASE;
            float2 a0 = *(const float2*)(p + 0);
            float2 a1 = *(const float2*)(p + 2);
            float2 a2 = *(const float2*)(p + 4);
            float2 a3 = *(const float2*)(p + 6);
            float2 a4 = *(const float2*)(p + 8);
            float x0 = a0.x, x1 = a0.y, x2 = a1.x, x3 = a1.y, x4 = a2.x;
            float x5 = a2.y, x6 = a3.x, x7 = a3.y, x8 = a4.x, x9 = a4.y;
            float m = fmaxf(x0, x1);
            m = fmaxf(m, x2); m = fmaxf(m, x3); m = fmaxf(m, x4);
            m = fmaxf(m, x5); m = fmaxf(m, x6); m = fmaxf(m, x7);
            m = fmaxf(m, x8); m = fmaxf(m, x9);
            // softmax((x - m) * 100); expected value of digits
            float e0v = __expf((x0 - m) * 100.0f);
            float e1v = __expf((x1 - m) * 100.0f);
            float e2v = __expf((x2 - m) * 100.0f);
            float e3v = __expf((x3 - m) * 100.0f);
            float e4v = __expf((x4 - m) * 100.0f);
            float e5v = __expf((x5 - m) * 100.0f);
            float e6v = __expf((x6 - m) * 100.0f);
            float e7v = __expf((x7 - m) * 100.0f);
            float e8v = __expf((x8 - m) * 100.0f);
            float e9v = __expf((x9 - m) * 100.0f);
            float den = e0v + e1v + e2v + e3v + e4v + e5v + e6v + e7v + e8v + e9v;
            float num = e1v * 1.0f + e2v * 2.0f + e3v * 3.0f + e4v * 4.0f +
                        e5v * 5.0f + e6v * 6.0f + e7v * 7.0f + e8v * 8.0f + e9v * 9.0f;
            float expected = num / den;
            int el = s / 72;
            int rem = s - el * 72;               // node*8 + d
            s_slot[el * 73 + rem] = expected * powv;
        }
    }

    __syncthreads();

    // ---- phase 2: DAG, one thread per element ----
    if (tid < EPB) {
        float vmag[NT], sgn[NT], logm[NT], sv[NT];
        #pragma unroll
        for (int n = 0; n < NI; ++n) {
            float v = 0.0f;
            #pragma unroll
            for (int d = 0; d < DTOT; ++d) v += s_slot[tid * 73 + n * 8 + d];
            v = fminf(fmaxf(v, MAG_MIN), MAG_MAX);
            vmag[n] = v;
            sgn[n]  = s_vs[tid * NT + n];
            logm[n] = logf(v);
            sv[n]   = sgn[n] * v;
        }
        #pragma unroll
        for (int n = NI; n < NT; ++n) {
            vmag[n] = 0.0f; sgn[n] = 0.0f;
            logm[n] = logf(MAG_MIN);             // log(max(0,1e-12))
            sv[n]   = 0.0f;
        }

        #pragma unroll
        for (int step = 0; step < DEPTH; ++step) {
            const int valid = NI + step;
            float g  = s_G[tid * 9 + step];
            float og = 1.0f - g;
            float R = 0.0f;
            float prod = 1.0f;
            #pragma unroll
            for (int n = 0; n < NT; ++n) {
                if (n < valid) {                 // compile-time after unroll
                    float o = s_O[tid * 137 + step * NT + n];
                    float mixed = logm[n] * og + sv[n] * g;
                    R += o * mixed;
                    float w = sgn[n] * fabsf(o) * 2.0f + 1.0f;
                    prod *= w;
                }
            }
            float linear_sign = tanh_fast(R * 10000.0f);
            float log_sign    = tanh_fast(prod * 10000.0f);
            float s_new = g * linear_sign + og * log_sign;
            float linear_mag  = fminf(fabsf(R), MAG_MAX);
            float Rc = fminf(fmaxf(R, -LOG_LIM), LOG_LIM);
            float log_mag_res = expf(Rc);
            float m_new = g * linear_mag + og * log_mag_res;
            m_new = fminf(fmaxf(m_new, MAG_MIN), MAG_MAX);
            s_new = fminf(fmaxf(s_new, -1.0f), 1.0f);
            vmag[valid] = m_new;
            sgn[valid]  = s_new;
            logm[valid] = logf(m_new);           // m_new >= MAG_MIN
            sv[valid]   = s_new * m_new;
        }
        out[e0 + tid] = sgn[NT - 1] * vmag[NT - 1];
    }
}

extern "C" void kernel_launch(void* const* d_in, const int* in_sizes, int n_in,
                              void* d_out, int out_size, void* d_ws, size_t ws_size,
                              hipStream_t stream) {
    const float* dl  = (const float*)d_in[0];   // digit_logits [B,T,9,8,10]
    const float* vsg = (const float*)d_in[1];   // V_sign       [B,T,17]
    const float* Og  = (const float*)d_in[2];   // O            [B,T,8,17]
    const float* Gg  = (const float*)d_in[3];   // G            [B,T,8]
    float* out = (float*)d_out;                 // [B,T] float32

    const int ne = out_size;                    // 32768
    const int blocks = ne / EPB;                // 1024
    dag_exec_kernel<<<blocks, THREADS, 0, stream>>>(dl, vsg, Og, Gg, out);
}